// Round 2
// baseline (172.440 us; speedup 1.0000x reference)
//
#include <hip/hip_runtime.h>

// Problem constants (fixed by setup_inputs)
constexpr int B   = 8;
constexpr int L   = 4096;
constexpr int D   = 768;
constexpr int S   = 32;
constexpr int G   = 16;
constexpr int TPG = 4;
constexpr int T   = G * TPG;   // 64

__global__ __launch_bounds__(256) void span_sim_kernel(
    const float* __restrict__ sen,    // [B,L,D]
    const float* __restrict__ arg,    // [B,S,T,D]
    const float* __restrict__ mask,   // [B,S,G]
    const int*   __restrict__ sstart, // [B,S]
    const int*   __restrict__ slen,   // [B,S]
    const int*   __restrict__ offp,   // [1]
    float*       __restrict__ out)    // [B,S,G]
{
    const int bs   = blockIdx.x;      // b*S + s
    const int b    = bs / S;
    const int tid  = threadIdx.x;
    const int lane = tid & 63;
    const int wave = tid >> 6;

    const int offset = offp[0];
    const int st = sstart[bs];
    const int ln = slen[bs];
    int lo = st - offset;           if (lo < 0) lo = 0;
    int hi = st + ln + 1 + offset;  if (hi > L) hi = L;
    const int cnt = hi - lo;        // always >= 1 here

    __shared__ float span[D];

    // ---- Phase 1: span mean. 256 threads x 3 columns, coalesced rows.
    const float* srow = sen + ((size_t)b * L + lo) * D;
    float a0 = 0.f, a1 = 0.f, a2 = 0.f;
    #pragma unroll 4
    for (int r = 0; r < cnt; ++r) {
        const float* p = srow + (size_t)r * D;
        a0 += p[tid];
        a1 += p[tid + 256];
        a2 += p[tid + 512];
    }
    const float inv = 1.0f / (float)cnt;
    span[tid]       = a0 * inv;
    span[tid + 256] = a1 * inv;
    span[tid + 512] = a2 * inv;
    __syncthreads();

    // ---- Phase 2: per-lane span fragment (3 x float4; d = k*256 + lane*4)
    const float4* sp4 = reinterpret_cast<const float4*>(span);
    const float4 s0 = sp4[lane];
    const float4 s1 = sp4[lane + 64];
    const float4 s2 = sp4[lane + 128];

    // wave w handles templates [w*16, w*16+16) == groups [w*4, w*4+4)
    const float4* abase = reinterpret_cast<const float4*>(arg + (size_t)bs * T * D);
    float gmax[4];
    #pragma unroll
    for (int i = 0; i < 16; ++i) {
        const int t = wave * 16 + i;
        const float4* a4 = abase + (size_t)t * (D / 4);
        const float4 v0 = a4[lane];
        const float4 v1 = a4[lane + 64];
        const float4 v2 = a4[lane + 128];
        float d = 0.f, x;
        x = v0.x - s0.x; d += x * x;  x = v0.y - s0.y; d += x * x;
        x = v0.z - s0.z; d += x * x;  x = v0.w - s0.w; d += x * x;
        x = v1.x - s1.x; d += x * x;  x = v1.y - s1.y; d += x * x;
        x = v1.z - s1.z; d += x * x;  x = v1.w - s1.w; d += x * x;
        x = v2.x - s2.x; d += x * x;  x = v2.y - s2.y; d += x * x;
        x = v2.z - s2.z; d += x * x;  x = v2.w - s2.w; d += x * x;
        // 64-lane butterfly reduce (all lanes end with the sum)
        #pragma unroll
        for (int o = 32; o >= 1; o >>= 1) d += __shfl_xor(d, o, 64);
        const float lg = -d;
        const int j = i >> 2;                 // static (loop fully unrolled)
        if ((i & 3) == 0) gmax[j] = lg;
        else              gmax[j] = fmaxf(gmax[j], lg);
    }

    if (lane == 0) {
        float*       o  = out  + (size_t)bs * G + wave * 4;
        const float* mk = mask + (size_t)bs * G + wave * 4;
        o[0] = gmax[0] * mk[0];
        o[1] = gmax[1] * mk[1];
        o[2] = gmax[2] * mk[2];
        o[3] = gmax[3] * mk[3];
    }
}

extern "C" void kernel_launch(void* const* d_in, const int* in_sizes, int n_in,
                              void* d_out, int out_size, void* d_ws, size_t ws_size,
                              hipStream_t stream) {
    const float* sen    = (const float*)d_in[0];
    const float* arg    = (const float*)d_in[1];
    const float* mask   = (const float*)d_in[2];
    const int*   sstart = (const int*)d_in[3];
    const int*   slen   = (const int*)d_in[4];
    const int*   offp   = (const int*)d_in[5];
    float*       out    = (float*)d_out;

    span_sim_kernel<<<B * S, 256, 0, stream>>>(sen, arg, mask, sstart, slen, offp, out);
}

// Round 4
// 171.388 us; speedup vs baseline: 1.0061x; 1.0061x over previous
//
#include <hip/hip_runtime.h>

// Problem constants (fixed by setup_inputs)
constexpr int B   = 8;
constexpr int L   = 4096;
constexpr int D   = 768;
constexpr int S   = 32;
constexpr int G   = 16;
constexpr int TPG = 4;
constexpr int T   = G * TPG;   // 64

// One block per (b,s): 1024 threads = 16 waves (4 waves/SIMD for latency hiding).
// Phase 1: 4-way row-split mean-pool -> LDS. Phase 2: wave g owns group g.
__global__ __launch_bounds__(1024) void span_sim_kernel(
    const float* __restrict__ sen,    // [B,L,D]
    const float* __restrict__ arg,    // [B,S,T,D]
    const float* __restrict__ mask,   // [B,S,G]
    const int*   __restrict__ sstart, // [B,S]
    const int*   __restrict__ slen,   // [B,S]
    const int*   __restrict__ offp,   // [1]
    float*       __restrict__ out)    // [B,S,G]
{
    const int bs   = blockIdx.x;      // b*S + s
    const int b    = bs >> 5;         // / S
    const int tid  = threadIdx.x;
    const int lane = tid & 63;
    const int wave = tid >> 6;        // 0..15 == template group

    const int offset = offp[0];
    const int st = sstart[bs];
    const int ln = slen[bs];
    int lo = st - offset;           if (lo < 0) lo = 0;
    int hi = st + ln + 1 + offset;  if (hi > L) hi = L;
    const int cnt = hi - lo;        // >= 1

    __shared__ float part[4][D];    // 12 KB partial sums
    __shared__ float span[D];       // 3 KB mean

    // ---- Phase 1: mean over span rows, rows split 4 ways.
    const int c  = tid & 255;       // column base; owns c, c+256, c+512
    const int rq = tid >> 8;        // row-quarter 0..3
    const float* srow = sen + ((size_t)b * L + lo) * D;
    float a0 = 0.f, a1 = 0.f, a2 = 0.f;
    #pragma unroll 4
    for (int r = rq; r < cnt; r += 4) {
        const float* p = srow + (size_t)r * D;
        a0 += p[c];
        a1 += p[c + 256];
        a2 += p[c + 512];
    }
    part[rq][c]       = a0;
    part[rq][c + 256] = a1;
    part[rq][c + 512] = a2;
    __syncthreads();

    if (tid < 256) {
        const float inv = 1.0f / (float)cnt;
        #pragma unroll
        for (int k = 0; k < 3; ++k) {
            const int j = tid + k * 256;
            span[j] = (part[0][j] + part[1][j] + part[2][j] + part[3][j]) * inv;
        }
    }
    __syncthreads();

    // ---- Phase 2: wave g computes group g's 4 templates, then segmented max.
    const float4* sp4 = reinterpret_cast<const float4*>(span);
    const float4 s0 = sp4[lane];
    const float4 s1 = sp4[lane + 64];
    const float4 s2 = sp4[lane + 128];

    const float4* abase = reinterpret_cast<const float4*>(arg + (size_t)bs * T * D);
    float dist[4];
    #pragma unroll
    for (int i = 0; i < 4; ++i) {
        const float4* a4 = abase + (size_t)(wave * 4 + i) * (D / 4);
        const float4 v0 = a4[lane];
        const float4 v1 = a4[lane + 64];
        const float4 v2 = a4[lane + 128];
        float d = 0.f, x;
        x = v0.x - s0.x; d += x * x;  x = v0.y - s0.y; d += x * x;
        x = v0.z - s0.z; d += x * x;  x = v0.w - s0.w; d += x * x;
        x = v1.x - s1.x; d += x * x;  x = v1.y - s1.y; d += x * x;
        x = v1.z - s1.z; d += x * x;  x = v1.w - s1.w; d += x * x;
        x = v2.x - s2.x; d += x * x;  x = v2.y - s2.y; d += x * x;
        x = v2.z - s2.z; d += x * x;  x = v2.w - s2.w; d += x * x;
        dist[i] = d;
    }
    // 4 independent butterfly chains, interleaved so they pipeline.
    #pragma unroll
    for (int o = 32; o >= 1; o >>= 1) {
        #pragma unroll
        for (int i = 0; i < 4; ++i) dist[i] += __shfl_xor(dist[i], o, 64);
    }
    if (lane == 0) {
        const float m = fmaxf(fmaxf(-dist[0], -dist[1]), fmaxf(-dist[2], -dist[3]));
        out[(size_t)bs * G + wave] = m * mask[(size_t)bs * G + wave];
    }
}

extern "C" void kernel_launch(void* const* d_in, const int* in_sizes, int n_in,
                              void* d_out, int out_size, void* d_ws, size_t ws_size,
                              hipStream_t stream) {
    const float* sen    = (const float*)d_in[0];
    const float* arg    = (const float*)d_in[1];
    const float* mask   = (const float*)d_in[2];
    const int*   sstart = (const int*)d_in[3];
    const int*   slen   = (const int*)d_in[4];
    const int*   offp   = (const int*)d_in[5];
    float*       out    = (float*)d_out;

    span_sim_kernel<<<B * S, 1024, 0, stream>>>(sen, arg, mask, sstart, slen, offp, out);
}